// Round 1
// baseline (176.527 us; speedup 1.0000x reference)
//
#include <hip/hip_runtime.h>
#include <stdint.h>

#define NUM_CLASS 10000
#define FEATDIM   512
#define BATCH     4096
#define MROWS     8192            // soft rows 0..4095, hard rows 4096..8191
#define BM        128
#define BN        128
#define BK        64
#define NTILES    79              // ceil(10000/128)
#define NSPLIT    8
#define ROWTILES  64              // 8192/128
#define WPAD_ROWS 10112           // 79*128

typedef float  f32x4  __attribute__((ext_vector_type(4)));
typedef __bf16 bf16x8 __attribute__((ext_vector_type(8)));

__device__ __forceinline__ unsigned short f2bf(float f) {
  unsigned u = __float_as_uint(f);
  u += 0x7FFFu + ((u >> 16) & 1u);        // round-to-nearest-even
  return (unsigned short)(u >> 16);
}

__device__ __forceinline__ void gll16(const void* g, void* l) {
  __builtin_amdgcn_global_load_lds(
      (const __attribute__((address_space(1))) void*)g,
      (__attribute__((address_space(3))) void*)l,
      16, 0, 0);
}

// ---- convert soft_x|hard_x -> bf16 X2 [8192][512] ----
__global__ void cvt_x_kernel(const float* __restrict__ sx,
                             const float* __restrict__ hx,
                             uint4* __restrict__ X2) {
  int idx = blockIdx.x * 256 + threadIdx.x;      // 524288 threads, 8 elems each
  const int half = BATCH * FEATDIM / 8;          // 262144
  const float4* src = (idx < half) ? ((const float4*)sx) + (size_t)idx * 2
                                   : ((const float4*)hx) + (size_t)(idx - half) * 2;
  float4 a = src[0], b = src[1];
  uint4 o;
  o.x = (unsigned)f2bf(a.x) | ((unsigned)f2bf(a.y) << 16);
  o.y = (unsigned)f2bf(a.z) | ((unsigned)f2bf(a.w) << 16);
  o.z = (unsigned)f2bf(b.x) | ((unsigned)f2bf(b.y) << 16);
  o.w = (unsigned)f2bf(b.z) | ((unsigned)f2bf(b.w) << 16);
  X2[idx] = o;
}

// ---- convert weight -> bf16 W2 [10112][512], pad rows zeroed ----
__global__ void cvt_w_kernel(const float* __restrict__ wt, uint4* __restrict__ W2) {
  int idx = blockIdx.x * 256 + threadIdx.x;      // 647168 threads
  int row = idx >> 6;                            // 64 uint4 per row
  uint4 o = {0u, 0u, 0u, 0u};
  if (row < NUM_CLASS) {
    const float4* src = ((const float4*)wt) + (size_t)idx * 2;
    float4 a = src[0], b = src[1];
    o.x = (unsigned)f2bf(a.x) | ((unsigned)f2bf(a.y) << 16);
    o.y = (unsigned)f2bf(a.z) | ((unsigned)f2bf(a.w) << 16);
    o.z = (unsigned)f2bf(b.x) | ((unsigned)f2bf(b.y) << 16);
    o.w = (unsigned)f2bf(b.z) | ((unsigned)f2bf(b.w) << 16);
  }
  W2[idx] = o;
}

// ---- per-row: target logits (f32 exact) + quantization sum ----
__global__ void rowstats_kernel(const float* __restrict__ sx, const float* __restrict__ hx,
                                const int* __restrict__ tgt,
                                const float* __restrict__ centers,
                                const float* __restrict__ weight,
                                float* __restrict__ tlogit, float* __restrict__ quant) {
  int row  = blockIdx.x * 4 + (threadIdx.x >> 6);
  int lane = threadIdx.x & 63;
  int t = tgt[row];
  const float4* s4 = (const float4*)(sx + (size_t)row * FEATDIM);
  const float4* h4 = (const float4*)(hx + (size_t)row * FEATDIM);
  const float4* c4 = (const float4*)(centers + (size_t)t * FEATDIM);
  const float4* w4 = (const float4*)(weight + (size_t)t * FEATDIM);
  float qs = 0.f, ds = 0.f, dh = 0.f;
#pragma unroll
  for (int j = 0; j < 2; ++j) {
    int i = lane + j * 64;
    float4 s = s4[i], h = h4[i], c = c4[i], w = w4[i];
    float d0 = s.x - c.x, d1 = s.y - c.y, d2 = s.z - c.z, d3 = s.w - c.w;
    float e0 = h.x - c.x, e1 = h.y - c.y, e2 = h.z - c.z, e3 = h.w - c.w;
    qs += d0*d0 + d1*d1 + d2*d2 + d3*d3 + e0*e0 + e1*e1 + e2*e2 + e3*e3;
    ds += s.x*w.x + s.y*w.y + s.z*w.z + s.w*w.w;
    dh += h.x*w.x + h.y*w.y + h.z*w.z + h.w*w.w;
  }
#pragma unroll
  for (int m = 1; m < 64; m <<= 1) {
    qs += __shfl_xor(qs, m);
    ds += __shfl_xor(ds, m);
    dh += __shfl_xor(dh, m);
  }
  if (lane == 0) {
    tlogit[row]         = ds;
    tlogit[BATCH + row] = dh;
    atomicAdd(quant, qs);
  }
}

// ---- fused GEMM + sum-of-exp over class axis ----
// grid: NSPLIT*ROWTILES, bid = chunk*64 + rowtile (chunk-major for W L2 locality)
__launch_bounds__(256, 2)
__global__ void gemm_lse_kernel(const char* __restrict__ X2, const char* __restrict__ W2,
                                float* __restrict__ sumexp) {
  __shared__ char ldsA[BM * BK * 2];   // 16 KB, rows of X tile, XOR-swizzled
  __shared__ char ldsB[BN * BK * 2];   // 16 KB, rows of W tile (= output cols)

  const int tid  = threadIdx.x;
  const int lane = tid & 63;
  const int w    = tid >> 6;
  const int wm   = w >> 1;          // 2x2 wave grid, each wave 64x64
  const int wn   = w & 1;
  const int chunk   = blockIdx.x >> 6;
  const int rowtile = blockIdx.x & 63;
  const int nt0 = (chunk * NTILES) / NSPLIT;
  const int nt1 = ((chunk + 1) * NTILES) / NSPLIT;

  // staging: 16 segs of 1KB per tile; wave w stages segs w*4..w*4+3 of each tile.
  // LDS dest is linear (base + lane*16); source is inverse-swizzled so that the
  // effective LDS layout is lds[row*128 + (kb ^ ((row&7)<<4))].
  int srow[4], skb[4];
#pragma unroll
  for (int j = 0; j < 4; ++j) {
    int seg = w * 4 + j;
    int o = seg * 1024 + lane * 16;
    int r = o >> 7;
    srow[j] = r;
    skb[j]  = (o & 127) ^ ((r & 7) << 4);
  }

  float se[4][4];
#pragma unroll
  for (int mi = 0; mi < 4; ++mi)
#pragma unroll
    for (int r = 0; r < 4; ++r) se[mi][r] = 0.f;

  const int arow0 = rowtile * BM;

  for (int nt = nt0; nt < nt1; ++nt) {
    f32x4 acc[4][4];
#pragma unroll
    for (int mi = 0; mi < 4; ++mi)
#pragma unroll
      for (int ni = 0; ni < 4; ++ni) {
        f32x4 z = {0.f, 0.f, 0.f, 0.f};
        acc[mi][ni] = z;
      }
    const int brow0 = nt * BN;

#pragma unroll 1
    for (int ks = 0; ks < FEATDIM / BK; ++ks) {
      __syncthreads();                 // LDS reads of prev step done
#pragma unroll
      for (int j = 0; j < 4; ++j) {
        int seg = w * 4 + j;
        const char* ga = X2 + ((arow0 + srow[j]) * 1024 + ks * 128 + skb[j]);
        gll16(ga, ldsA + seg * 1024);
        const char* gb = W2 + ((brow0 + srow[j]) * 1024 + ks * 128 + skb[j]);
        gll16(gb, ldsB + seg * 1024);
      }
      __syncthreads();                 // drains vmcnt, staging complete

#pragma unroll
      for (int ksub = 0; ksub < 2; ++ksub) {
        bf16x8 a[4], b[4];
#pragma unroll
        for (int mi = 0; mi < 4; ++mi) {
          int r  = wm * 64 + mi * 16 + (lane & 15);
          int kb = (ksub * 64 + ((lane >> 4) << 4)) ^ ((r & 7) << 4);
          a[mi] = *(const bf16x8*)(ldsA + r * 128 + kb);
        }
#pragma unroll
        for (int ni = 0; ni < 4; ++ni) {
          int r  = wn * 64 + ni * 16 + (lane & 15);
          int kb = (ksub * 64 + ((lane >> 4) << 4)) ^ ((r & 7) << 4);
          b[ni] = *(const bf16x8*)(ldsB + r * 128 + kb);
        }
#pragma unroll
        for (int mi = 0; mi < 4; ++mi)
#pragma unroll
          for (int ni = 0; ni < 4; ++ni)
            acc[mi][ni] = __builtin_amdgcn_mfma_f32_16x16x32_bf16(a[mi], b[ni], acc[mi][ni], 0, 0, 0);
      }
    }

    // epilogue: sum exp over this 128-col tile; mask ragged cols >= NUM_CLASS
    const int colb = nt * BN + wn * 64 + (lane & 15);
#pragma unroll
    for (int ni = 0; ni < 4; ++ni) {
      bool ok = (colb + ni * 16) < NUM_CLASS;
#pragma unroll
      for (int mi = 0; mi < 4; ++mi)
#pragma unroll
        for (int r = 0; r < 4; ++r)
          if (ok) se[mi][r] += __expf(acc[mi][ni][r]);
    }
  }

  // C/D layout: col = lane&15 (summed over), row = (lane>>4)*4 + r
  // lanes sharing lane>>4 hold the same rows -> reduce over low 4 lane bits
#pragma unroll
  for (int m = 1; m < 16; m <<= 1)
#pragma unroll
    for (int mi = 0; mi < 4; ++mi)
#pragma unroll
      for (int r = 0; r < 4; ++r)
        se[mi][r] += __shfl_xor(se[mi][r], m);

  if ((lane & 15) == 0) {
#pragma unroll
    for (int mi = 0; mi < 4; ++mi)
#pragma unroll
      for (int r = 0; r < 4; ++r) {
        int grow = arow0 + wm * 64 + mi * 16 + ((lane >> 4) << 2) + r;
        atomicAdd(&sumexp[grow], se[mi][r]);
      }
  }
}

// ---- final scalar reduction ----
__global__ void finalize_kernel(const float* __restrict__ sumexp,
                                const float* __restrict__ tlogit,
                                const float* __restrict__ quant,
                                float* __restrict__ out) {
  int tid = threadIdx.x;     // 1024 threads
  float acc = 0.f;
  for (int i = tid; i < MROWS; i += 1024)
    acc += logf(sumexp[i]) - tlogit[i];
#pragma unroll
  for (int m = 1; m < 64; m <<= 1) acc += __shfl_xor(acc, m);
  __shared__ float red[16];
  if ((tid & 63) == 0) red[tid >> 6] = acc;
  __syncthreads();
  if (tid == 0) {
    float s = 0.f;
#pragma unroll
    for (int i = 0; i < 16; ++i) s += red[i];
    // loss = (ce1_sum + ce2_sum)/B + PARAM * 0.5 * qsum / B ; PARAM=0.5, B=4096
    out[0] = s * (1.0f / BATCH) + quant[0] * (1.0f / 16384.0f);
  }
}

extern "C" void kernel_launch(void* const* d_in, const int* in_sizes, int n_in,
                              void* d_out, int out_size, void* d_ws, size_t ws_size,
                              hipStream_t stream) {
  const float* sx = (const float*)d_in[0];
  const float* hx = (const float*)d_in[1];
  const int*   tg = (const int*)d_in[2];
  const float* ct = (const float*)d_in[3];
  const float* wt = (const float*)d_in[4];
  float* out = (float*)d_out;

  char* ws = (char*)d_ws;
  char* X2 = ws;                                               // 8,388,608 B
  char* W2 = ws + (size_t)MROWS * FEATDIM * 2;                 // 10,354,688 B
  size_t off = (size_t)MROWS * FEATDIM * 2 + (size_t)WPAD_ROWS * FEATDIM * 2;
  float* sumexp = (float*)(ws + off);                          // 8192 f32
  float* quant  = (float*)(ws + off + (size_t)MROWS * 4);      // 1 f32 (padded)
  float* tlogit = (float*)(ws + off + (size_t)MROWS * 4 + 256);// 8192 f32

  hipMemsetAsync(ws + off, 0, (size_t)MROWS * 4 + 256, stream);
  cvt_x_kernel<<<2048, 256, 0, stream>>>(sx, hx, (uint4*)X2);
  cvt_w_kernel<<<2528, 256, 0, stream>>>(wt, (uint4*)W2);
  rowstats_kernel<<<BATCH / 4, 256, 0, stream>>>(sx, hx, tg, ct, wt, tlogit, quant);
  gemm_lse_kernel<<<NSPLIT * ROWTILES, 256, 0, stream>>>(X2, W2, sumexp);
  finalize_kernel<<<1, 1024, 0, stream>>>(sumexp, tlogit, quant, out);
}

// Round 2
// 114.259 us; speedup vs baseline: 1.5450x; 1.5450x over previous
//
#include <hip/hip_runtime.h>
#include <stdint.h>

#define NUM_CLASS 10000
#define FEATDIM   512
#define BATCH     4096
#define MROWS     8192            // soft rows 0..4095, hard rows 4096..8191
#define BM        128
#define BN        128
#define BK        64
#define NTILES    79              // ceil(10000/128)
#define NSPLIT    16
#define ROWTILES  64              // 8192/128
#define WPAD_ROWS 10112           // 79*128

// prep kernel block ranges
#define PB_CVTX   2048            // 524288 threads
#define PB_CVTW   2528            // 647168 threads
#define PB_ROWS   1024            // 4096 rows, 4/block
#define PB_ZERO   8               // zero sumexp (8192 f32)
#define PB_TOTAL  (PB_CVTX + PB_CVTW + PB_ROWS + PB_ZERO)

typedef float  f32x4  __attribute__((ext_vector_type(4)));
typedef __bf16 bf16x8 __attribute__((ext_vector_type(8)));

__device__ __forceinline__ unsigned short f2bf(float f) {
  unsigned u = __float_as_uint(f);
  u += 0x7FFFu + ((u >> 16) & 1u);        // round-to-nearest-even
  return (unsigned short)(u >> 16);
}

__device__ __forceinline__ void gll16(const void* g, void* l) {
  __builtin_amdgcn_global_load_lds(
      (const __attribute__((address_space(1))) void*)g,
      (__attribute__((address_space(3))) void*)l,
      16, 0, 0);
}

__device__ __forceinline__ uint4 pack_bf16x8(float4 a, float4 b) {
  uint4 o;
  o.x = (unsigned)f2bf(a.x) | ((unsigned)f2bf(a.y) << 16);
  o.y = (unsigned)f2bf(a.z) | ((unsigned)f2bf(a.w) << 16);
  o.z = (unsigned)f2bf(b.x) | ((unsigned)f2bf(b.y) << 16);
  o.w = (unsigned)f2bf(b.z) | ((unsigned)f2bf(b.w) << 16);
  return o;
}

// ---- fused prep: cvt X, cvt W, per-row stats, zero sumexp ----
__global__ void prep_kernel(const float* __restrict__ sx, const float* __restrict__ hx,
                            const int* __restrict__ tgt,
                            const float* __restrict__ centers,
                            const float* __restrict__ weight,
                            uint4* __restrict__ X2, uint4* __restrict__ W2,
                            float* __restrict__ tlogit, float* __restrict__ qrow,
                            float4* __restrict__ sumexp4) {
  const int b   = blockIdx.x;
  const int tid = threadIdx.x;

  if (b < PB_CVTX) {
    // soft_x|hard_x -> bf16 X2 [8192][512]
    int idx = b * 256 + tid;                       // 8 floats each
    const int half = BATCH * FEATDIM / 8;          // 262144
    const float4* src = (idx < half) ? ((const float4*)sx) + (size_t)idx * 2
                                     : ((const float4*)hx) + (size_t)(idx - half) * 2;
    X2[idx] = pack_bf16x8(src[0], src[1]);
    return;
  }
  if (b < PB_CVTX + PB_CVTW) {
    // weight -> bf16 W2 [10112][512], pad rows zeroed
    int idx = (b - PB_CVTX) * 256 + tid;
    int row = idx >> 6;                            // 64 uint4 per row
    uint4 o = {0u, 0u, 0u, 0u};
    if (row < NUM_CLASS) {
      const float4* src = ((const float4*)weight) + (size_t)idx * 2;
      o = pack_bf16x8(src[0], src[1]);
    }
    W2[idx] = o;
    return;
  }
  if (b < PB_CVTX + PB_CVTW + PB_ROWS) {
    // per-row: target logits (f32 exact) + quantization sum
    int row  = (b - PB_CVTX - PB_CVTW) * 4 + (tid >> 6);
    int lane = tid & 63;
    int t = tgt[row];
    const float4* s4 = (const float4*)(sx + (size_t)row * FEATDIM);
    const float4* h4 = (const float4*)(hx + (size_t)row * FEATDIM);
    const float4* c4 = (const float4*)(centers + (size_t)t * FEATDIM);
    const float4* w4 = (const float4*)(weight + (size_t)t * FEATDIM);
    float qs = 0.f, ds = 0.f, dh = 0.f;
#pragma unroll
    for (int j = 0; j < 2; ++j) {
      int i = lane + j * 64;
      float4 s = s4[i], h = h4[i], c = c4[i], w = w4[i];
      float d0 = s.x - c.x, d1 = s.y - c.y, d2 = s.z - c.z, d3 = s.w - c.w;
      float e0 = h.x - c.x, e1 = h.y - c.y, e2 = h.z - c.z, e3 = h.w - c.w;
      qs += d0*d0 + d1*d1 + d2*d2 + d3*d3 + e0*e0 + e1*e1 + e2*e2 + e3*e3;
      ds += s.x*w.x + s.y*w.y + s.z*w.z + s.w*w.w;
      dh += h.x*w.x + h.y*w.y + h.z*w.z + h.w*w.w;
    }
#pragma unroll
    for (int m = 1; m < 64; m <<= 1) {
      qs += __shfl_xor(qs, m);
      ds += __shfl_xor(ds, m);
      dh += __shfl_xor(dh, m);
    }
    if (lane == 0) {
      tlogit[row]         = ds;
      tlogit[BATCH + row] = dh;
      qrow[row]           = qs;
    }
    return;
  }
  // zero sumexp: 8 blocks x 256 threads x 1 float4 = 8192 f32
  {
    int idx = (b - PB_CVTX - PB_CVTW - PB_ROWS) * 256 + tid;
    float4 z = {0.f, 0.f, 0.f, 0.f};
    sumexp4[idx] = z;
  }
}

// ---- fused GEMM + sum-of-exp over class axis ----
// grid: NSPLIT*ROWTILES, bid = chunk*64 + rowtile (chunk-major for W L2 locality)
__launch_bounds__(256, 4)
__global__ void gemm_lse_kernel(const char* __restrict__ X2, const char* __restrict__ W2,
                                float* __restrict__ sumexp) {
  __shared__ char ldsA[BM * BK * 2];   // 16 KB, rows of X tile, XOR-swizzled
  __shared__ char ldsB[BN * BK * 2];   // 16 KB, rows of W tile (= output cols)

  const int tid  = threadIdx.x;
  const int lane = tid & 63;
  const int w    = tid >> 6;
  const int wm   = w >> 1;          // 2x2 wave grid, each wave 64x64
  const int wn   = w & 1;
  const int chunk   = blockIdx.x >> 6;
  const int rowtile = blockIdx.x & 63;
  const int nt0 = (chunk * NTILES) / NSPLIT;
  const int nt1 = ((chunk + 1) * NTILES) / NSPLIT;

  // staging: 16 segs of 1KB per tile; wave w stages segs w*4..w*4+3 of each tile.
  // LDS dest is linear (base + lane*16); source is inverse-swizzled so that the
  // effective LDS layout is lds[row*128 + (kb ^ ((row&7)<<4))].
  int srow[4], skb[4];
#pragma unroll
  for (int j = 0; j < 4; ++j) {
    int seg = w * 4 + j;
    int o = seg * 1024 + lane * 16;
    int r = o >> 7;
    srow[j] = r;
    skb[j]  = (o & 127) ^ ((r & 7) << 4);
  }

  float se[4][4];
#pragma unroll
  for (int mi = 0; mi < 4; ++mi)
#pragma unroll
    for (int r = 0; r < 4; ++r) se[mi][r] = 0.f;

  const int arow0 = rowtile * BM;

  for (int nt = nt0; nt < nt1; ++nt) {
    f32x4 acc[4][4];
#pragma unroll
    for (int mi = 0; mi < 4; ++mi)
#pragma unroll
      for (int ni = 0; ni < 4; ++ni) {
        f32x4 z = {0.f, 0.f, 0.f, 0.f};
        acc[mi][ni] = z;
      }
    const int brow0 = nt * BN;

#pragma unroll 1
    for (int ks = 0; ks < FEATDIM / BK; ++ks) {
      __syncthreads();                 // LDS reads of prev step done
#pragma unroll
      for (int j = 0; j < 4; ++j) {
        int seg = w * 4 + j;
        const char* ga = X2 + ((arow0 + srow[j]) * 1024 + ks * 128 + skb[j]);
        gll16(ga, ldsA + seg * 1024);
        const char* gb = W2 + ((brow0 + srow[j]) * 1024 + ks * 128 + skb[j]);
        gll16(gb, ldsB + seg * 1024);
      }
      __syncthreads();                 // drains vmcnt, staging complete

#pragma unroll
      for (int ksub = 0; ksub < 2; ++ksub) {
        bf16x8 a[4], b[4];
#pragma unroll
        for (int mi = 0; mi < 4; ++mi) {
          int r  = wm * 64 + mi * 16 + (lane & 15);
          int kb = (ksub * 64 + ((lane >> 4) << 4)) ^ ((r & 7) << 4);
          a[mi] = *(const bf16x8*)(ldsA + r * 128 + kb);
        }
#pragma unroll
        for (int ni = 0; ni < 4; ++ni) {
          int r  = wn * 64 + ni * 16 + (lane & 15);
          int kb = (ksub * 64 + ((lane >> 4) << 4)) ^ ((r & 7) << 4);
          b[ni] = *(const bf16x8*)(ldsB + r * 128 + kb);
        }
#pragma unroll
        for (int mi = 0; mi < 4; ++mi)
#pragma unroll
          for (int ni = 0; ni < 4; ++ni)
            acc[mi][ni] = __builtin_amdgcn_mfma_f32_16x16x32_bf16(a[mi], b[ni], acc[mi][ni], 0, 0, 0);
      }
    }

    // epilogue: sum exp over this 128-col tile; mask ragged cols >= NUM_CLASS
    const int colb = nt * BN + wn * 64 + (lane & 15);
#pragma unroll
    for (int ni = 0; ni < 4; ++ni) {
      bool ok = (colb + ni * 16) < NUM_CLASS;
#pragma unroll
      for (int mi = 0; mi < 4; ++mi)
#pragma unroll
        for (int r = 0; r < 4; ++r)
          if (ok) se[mi][r] += __expf(acc[mi][ni][r]);
    }
  }

  // C/D layout: col = lane&15 (summed over), row = (lane>>4)*4 + r
  // lanes sharing lane>>4 hold the same rows -> reduce over low 4 lane bits
#pragma unroll
  for (int m = 1; m < 16; m <<= 1)
#pragma unroll
    for (int mi = 0; mi < 4; ++mi)
#pragma unroll
      for (int r = 0; r < 4; ++r)
        se[mi][r] += __shfl_xor(se[mi][r], m);

  if ((lane & 15) == 0) {
#pragma unroll
    for (int mi = 0; mi < 4; ++mi)
#pragma unroll
      for (int r = 0; r < 4; ++r) {
        int grow = arow0 + wm * 64 + mi * 16 + ((lane >> 4) << 2) + r;
        atomicAdd(&sumexp[grow], se[mi][r]);
      }
  }
}

// ---- final scalar reduction ----
__global__ void finalize_kernel(const float* __restrict__ sumexp,
                                const float* __restrict__ tlogit,
                                const float* __restrict__ qrow,
                                float* __restrict__ out) {
  int tid = threadIdx.x;     // 1024 threads
  float acc = 0.f, q = 0.f;
  for (int i = tid; i < MROWS; i += 1024)
    acc += logf(sumexp[i]) - tlogit[i];
  for (int i = tid; i < BATCH; i += 1024)
    q += qrow[i];
#pragma unroll
  for (int m = 1; m < 64; m <<= 1) {
    acc += __shfl_xor(acc, m);
    q   += __shfl_xor(q, m);
  }
  __shared__ float redA[16], redQ[16];
  if ((tid & 63) == 0) { redA[tid >> 6] = acc; redQ[tid >> 6] = q; }
  __syncthreads();
  if (tid == 0) {
    float s = 0.f, qq = 0.f;
#pragma unroll
    for (int i = 0; i < 16; ++i) { s += redA[i]; qq += redQ[i]; }
    // loss = (ce1_sum + ce2_sum)/B + PARAM * 0.5 * qsum / B ; PARAM=0.5, B=4096
    out[0] = s * (1.0f / BATCH) + qq * (1.0f / 16384.0f);
  }
}

extern "C" void kernel_launch(void* const* d_in, const int* in_sizes, int n_in,
                              void* d_out, int out_size, void* d_ws, size_t ws_size,
                              hipStream_t stream) {
  const float* sx = (const float*)d_in[0];
  const float* hx = (const float*)d_in[1];
  const int*   tg = (const int*)d_in[2];
  const float* ct = (const float*)d_in[3];
  const float* wt = (const float*)d_in[4];
  float* out = (float*)d_out;

  char* ws = (char*)d_ws;
  char* X2 = ws;                                               // 8,388,608 B
  char* W2 = ws + (size_t)MROWS * FEATDIM * 2;                 // 10,354,688 B
  size_t off = (size_t)MROWS * FEATDIM * 2 + (size_t)WPAD_ROWS * FEATDIM * 2;
  float* sumexp = (float*)(ws + off);                          // 8192 f32
  float* tlogit = (float*)(ws + off + (size_t)MROWS * 4);      // 8192 f32
  float* qrow   = (float*)(ws + off + (size_t)MROWS * 8);      // 4096 f32

  prep_kernel<<<PB_TOTAL, 256, 0, stream>>>(sx, hx, tg, ct, wt,
                                            (uint4*)X2, (uint4*)W2,
                                            tlogit, qrow, (float4*)sumexp);
  gemm_lse_kernel<<<NSPLIT * ROWTILES, 256, 0, stream>>>(X2, W2, sumexp);
  finalize_kernel<<<1, 1024, 0, stream>>>(sumexp, tlogit, qrow, out);
}

// Round 3
// 82.262 us; speedup vs baseline: 2.1459x; 1.3890x over previous
//
#include <hip/hip_runtime.h>
#include <stdint.h>

#define NUM_CLASS 10000
#define FEATDIM   512
#define BATCH     4096
#define MROWS     8192            // soft rows 0..4095, hard rows 4096..8191
#define BM        128
#define BN        128
#define BKF       128             // fp8 K-bytes per k-step
#define KSTEPS    (FEATDIM / BKF) // 4
#define NTILES    79              // ceil(10000/128)
#define NSPLIT    16
#define ROWTILES  64              // 8192/128
#define WPAD_ROWS 10112           // 79*128

// prep kernel block ranges (256 threads each)
#define PB_CVTX   1024            // 8192*512/16 = 262144 threads, 16 fp8/thread
#define PB_CVTW   1264            // 10112*512/16 = 323584 threads
#define PB_ROWS   1024            // 4096 rows, 4/block
#define PB_ZERO   8               // zero sumexp (8192 f32)
#define PB_TOTAL  (PB_CVTX + PB_CVTW + PB_ROWS + PB_ZERO)

typedef float f32x4 __attribute__((ext_vector_type(4)));
typedef int   i32x8 __attribute__((ext_vector_type(8)));

union F8frag { i32x8 v; uint4 q[2]; };

__device__ __forceinline__ void gll16(const void* g, void* l) {
  __builtin_amdgcn_global_load_lds(
      (const __attribute__((address_space(1))) void*)g,
      (__attribute__((address_space(3))) void*)l,
      16, 0, 0);
}

__device__ __forceinline__ unsigned pk_fp8x4(float4 a) {
  int v = __builtin_amdgcn_cvt_pk_fp8_f32(a.x, a.y, 0, false);
  v = __builtin_amdgcn_cvt_pk_fp8_f32(a.z, a.w, v, true);
  return (unsigned)v;
}

// ---- fused prep: cvt X->fp8, cvt W->fp8, per-row stats, zero sumexp ----
__global__ void prep_kernel(const float* __restrict__ sx, const float* __restrict__ hx,
                            const int* __restrict__ tgt,
                            const float* __restrict__ centers,
                            const float* __restrict__ weight,
                            uint4* __restrict__ X8, uint4* __restrict__ W8,
                            float* __restrict__ tlogit, float* __restrict__ qrow,
                            float4* __restrict__ sumexp4) {
  const int b   = blockIdx.x;
  const int tid = threadIdx.x;

  if (b < PB_CVTX) {
    // soft_x|hard_x -> fp8 X8 [8192][512]; 16 floats -> 16 bytes per thread
    int idx = b * 256 + tid;
    const int half = BATCH * FEATDIM / 16;         // 131072
    const float4* src = (idx < half) ? ((const float4*)sx) + (size_t)idx * 4
                                     : ((const float4*)hx) + (size_t)(idx - half) * 4;
    uint4 o;
    o.x = pk_fp8x4(src[0]);
    o.y = pk_fp8x4(src[1]);
    o.z = pk_fp8x4(src[2]);
    o.w = pk_fp8x4(src[3]);
    X8[idx] = o;
    return;
  }
  if (b < PB_CVTX + PB_CVTW) {
    // weight -> fp8 W8 [10112][512], pad rows zeroed
    int idx = (b - PB_CVTX) * 256 + tid;
    int row = idx >> 5;                            // 32 uint4 (512 B) per row
    uint4 o = {0u, 0u, 0u, 0u};
    if (row < NUM_CLASS) {
      const float4* src = ((const float4*)weight) + (size_t)idx * 4;
      o.x = pk_fp8x4(src[0]);
      o.y = pk_fp8x4(src[1]);
      o.z = pk_fp8x4(src[2]);
      o.w = pk_fp8x4(src[3]);
    }
    W8[idx] = o;
    return;
  }
  if (b < PB_CVTX + PB_CVTW + PB_ROWS) {
    // per-row: target logits (f32 exact) + quantization sum
    int row  = (b - PB_CVTX - PB_CVTW) * 4 + (tid >> 6);
    int lane = tid & 63;
    int t = tgt[row];
    const float4* s4 = (const float4*)(sx + (size_t)row * FEATDIM);
    const float4* h4 = (const float4*)(hx + (size_t)row * FEATDIM);
    const float4* c4 = (const float4*)(centers + (size_t)t * FEATDIM);
    const float4* w4 = (const float4*)(weight + (size_t)t * FEATDIM);
    float qs = 0.f, ds = 0.f, dh = 0.f;
#pragma unroll
    for (int j = 0; j < 2; ++j) {
      int i = lane + j * 64;
      float4 s = s4[i], h = h4[i], c = c4[i], w = w4[i];
      float d0 = s.x - c.x, d1 = s.y - c.y, d2 = s.z - c.z, d3 = s.w - c.w;
      float e0 = h.x - c.x, e1 = h.y - c.y, e2 = h.z - c.z, e3 = h.w - c.w;
      qs += d0*d0 + d1*d1 + d2*d2 + d3*d3 + e0*e0 + e1*e1 + e2*e2 + e3*e3;
      ds += s.x*w.x + s.y*w.y + s.z*w.z + s.w*w.w;
      dh += h.x*w.x + h.y*w.y + h.z*w.z + h.w*w.w;
    }
#pragma unroll
    for (int m = 1; m < 64; m <<= 1) {
      qs += __shfl_xor(qs, m);
      ds += __shfl_xor(ds, m);
      dh += __shfl_xor(dh, m);
    }
    if (lane == 0) {
      tlogit[row]         = ds;
      tlogit[BATCH + row] = dh;
      qrow[row]           = qs;
    }
    return;
  }
  // zero sumexp: 8 blocks x 256 threads x 1 float4 = 8192 f32
  {
    int idx = (b - PB_CVTX - PB_CVTW - PB_ROWS) * 256 + tid;
    float4 z = {0.f, 0.f, 0.f, 0.f};
    sumexp4[idx] = z;
  }
}

// ---- fused MX-fp8 GEMM + sum-of-exp over class axis ----
// grid: NSPLIT*ROWTILES, bid = chunk*64 + rowtile (chunk-major for W L2 locality)
__launch_bounds__(256, 3)
__global__ void gemm_lse_kernel(const char* __restrict__ X8, const char* __restrict__ W8,
                                float* __restrict__ sumexp) {
  __shared__ char ldsA[BM * BKF];   // 16 KB, rows of X tile, XOR-swizzled
  __shared__ char ldsB[BN * BKF];   // 16 KB, rows of W tile (= output cols)

  const int tid  = threadIdx.x;
  const int lane = tid & 63;
  const int w    = tid >> 6;
  const int wm   = w >> 1;          // 2x2 wave grid, each wave 64x64
  const int wn   = w & 1;
  const int chunk   = blockIdx.x >> 6;
  const int rowtile = blockIdx.x & 63;
  const int nt0 = (chunk * NTILES) / NSPLIT;
  const int nt1 = ((chunk + 1) * NTILES) / NSPLIT;

  // staging: 16 segs of 1KB per tile; wave w stages segs w*4..w*4+3 of each tile.
  // LDS dest is linear (base + lane*16); source is inverse-swizzled so that the
  // effective LDS layout is lds[row*128 + (kb ^ ((row&7)<<4))].
  int srow[4], skb[4];
#pragma unroll
  for (int j = 0; j < 4; ++j) {
    int seg = w * 4 + j;
    int o = seg * 1024 + lane * 16;
    int r = o >> 7;
    srow[j] = r;
    skb[j]  = (o & 127) ^ ((r & 7) << 4);
  }

  float se[4][4];
#pragma unroll
  for (int mi = 0; mi < 4; ++mi)
#pragma unroll
    for (int r = 0; r < 4; ++r) se[mi][r] = 0.f;

  const int arow0 = rowtile * BM;
  const int rl = lane & 15;
  const int kq = (lane >> 4) << 5;       // this lane's 32-byte K-chunk offset

  for (int nt = nt0; nt < nt1; ++nt) {
    f32x4 acc[4][4];
#pragma unroll
    for (int mi = 0; mi < 4; ++mi)
#pragma unroll
      for (int ni = 0; ni < 4; ++ni) {
        f32x4 z = {0.f, 0.f, 0.f, 0.f};
        acc[mi][ni] = z;
      }
    const int brow0 = nt * BN;

#pragma unroll 1
    for (int ks = 0; ks < KSTEPS; ++ks) {
      __syncthreads();                 // LDS reads of prev step done
#pragma unroll
      for (int j = 0; j < 4; ++j) {
        int seg = w * 4 + j;
        const char* ga = X8 + ((arow0 + srow[j]) * 512 + ks * 128 + skb[j]);
        gll16(ga, ldsA + seg * 1024);
        const char* gb = W8 + ((brow0 + srow[j]) * 512 + ks * 128 + skb[j]);
        gll16(gb, ldsB + seg * 1024);
      }
      __syncthreads();                 // drains vmcnt, staging complete

      F8frag a[4], b[4];
#pragma unroll
      for (int mi = 0; mi < 4; ++mi) {
        int r  = wm * 64 + mi * 16 + rl;
        int sr = (r & 7) << 4;
        const char* base = ldsA + r * 128;
        a[mi].q[0] = *(const uint4*)(base + (kq ^ sr));
        a[mi].q[1] = *(const uint4*)(base + ((kq + 16) ^ sr));
      }
#pragma unroll
      for (int ni = 0; ni < 4; ++ni) {
        int r  = wn * 64 + ni * 16 + rl;
        int sr = (r & 7) << 4;
        const char* base = ldsB + r * 128;
        b[ni].q[0] = *(const uint4*)(base + (kq ^ sr));
        b[ni].q[1] = *(const uint4*)(base + ((kq + 16) ^ sr));
      }
#pragma unroll
      for (int mi = 0; mi < 4; ++mi)
#pragma unroll
        for (int ni = 0; ni < 4; ++ni)
          acc[mi][ni] = __builtin_amdgcn_mfma_scale_f32_16x16x128_f8f6f4(
              a[mi].v, b[ni].v, acc[mi][ni],
              0, 0,                         // cbsz=FP8(A), blgp=FP8(B)
              0, 0x7F7F7F7F,                // opselA, scaleA = 1.0 (E8M0 127)
              0, 0x7F7F7F7F);               // opselB, scaleB = 1.0
    }

    // epilogue: sum exp over this 128-col tile; mask ragged cols >= NUM_CLASS
    const int colb = nt * BN + wn * 64 + rl;
#pragma unroll
    for (int ni = 0; ni < 4; ++ni) {
      bool ok = (colb + ni * 16) < NUM_CLASS;
#pragma unroll
      for (int mi = 0; mi < 4; ++mi)
#pragma unroll
        for (int r = 0; r < 4; ++r)
          if (ok) se[mi][r] += __expf(acc[mi][ni][r]);
    }
  }

  // C/D layout: col = lane&15 (summed over), row = (lane>>4)*4 + r
#pragma unroll
  for (int m = 1; m < 16; m <<= 1)
#pragma unroll
    for (int mi = 0; mi < 4; ++mi)
#pragma unroll
      for (int r = 0; r < 4; ++r)
        se[mi][r] += __shfl_xor(se[mi][r], m);

  if ((lane & 15) == 0) {
#pragma unroll
    for (int mi = 0; mi < 4; ++mi)
#pragma unroll
      for (int r = 0; r < 4; ++r) {
        int grow = arow0 + wm * 64 + mi * 16 + ((lane >> 4) << 2) + r;
        atomicAdd(&sumexp[grow], se[mi][r]);
      }
  }
}

// ---- final scalar reduction ----
__global__ void finalize_kernel(const float* __restrict__ sumexp,
                                const float* __restrict__ tlogit,
                                const float* __restrict__ qrow,
                                float* __restrict__ out) {
  int tid = threadIdx.x;     // 1024 threads
  float acc = 0.f, q = 0.f;
  for (int i = tid; i < MROWS; i += 1024)
    acc += logf(sumexp[i]) - tlogit[i];
  for (int i = tid; i < BATCH; i += 1024)
    q += qrow[i];
#pragma unroll
  for (int m = 1; m < 64; m <<= 1) {
    acc += __shfl_xor(acc, m);
    q   += __shfl_xor(q, m);
  }
  __shared__ float redA[16], redQ[16];
  if ((tid & 63) == 0) { redA[tid >> 6] = acc; redQ[tid >> 6] = q; }
  __syncthreads();
  if (tid == 0) {
    float s = 0.f, qq = 0.f;
#pragma unroll
    for (int i = 0; i < 16; ++i) { s += redA[i]; qq += redQ[i]; }
    // loss = (ce1_sum + ce2_sum)/B + PARAM * 0.5 * qsum / B ; PARAM=0.5, B=4096
    out[0] = s * (1.0f / BATCH) + qq * (1.0f / 16384.0f);
  }
}

extern "C" void kernel_launch(void* const* d_in, const int* in_sizes, int n_in,
                              void* d_out, int out_size, void* d_ws, size_t ws_size,
                              hipStream_t stream) {
  const float* sx = (const float*)d_in[0];
  const float* hx = (const float*)d_in[1];
  const int*   tg = (const int*)d_in[2];
  const float* ct = (const float*)d_in[3];
  const float* wt = (const float*)d_in[4];
  float* out = (float*)d_out;

  char* ws = (char*)d_ws;
  char* X8 = ws;                                               // 4,194,304 B
  char* W8 = ws + (size_t)MROWS * FEATDIM;                     // 5,177,344 B
  size_t off = (size_t)MROWS * FEATDIM + (size_t)WPAD_ROWS * FEATDIM;
  float* sumexp = (float*)(ws + off);                          // 8192 f32
  float* tlogit = (float*)(ws + off + (size_t)MROWS * 4);      // 8192 f32
  float* qrow   = (float*)(ws + off + (size_t)MROWS * 8);      // 4096 f32

  prep_kernel<<<PB_TOTAL, 256, 0, stream>>>(sx, hx, tg, ct, wt,
                                            (uint4*)X8, (uint4*)W8,
                                            tlogit, qrow, (float4*)sumexp);
  gemm_lse_kernel<<<NSPLIT * ROWTILES, 256, 0, stream>>>(X8, W8, sumexp);
  finalize_kernel<<<1, 1024, 0, stream>>>(sumexp, tlogit, qrow, out);
}

// Round 4
// 77.912 us; speedup vs baseline: 2.2657x; 1.0558x over previous
//
#include <hip/hip_runtime.h>
#include <stdint.h>

#define NUM_CLASS 10000
#define FEATDIM   512
#define BATCH     4096
#define MROWS     8192            // soft rows 0..4095, hard rows 4096..8191
#define BM        128
#define BN        128
#define BKF       128             // fp8 K-bytes per k-step
#define KSTEPS    (FEATDIM / BKF) // 4
#define NTILES    79              // ceil(10000/128)
#define NSPLIT    16
#define ROWTILES  64              // 8192/128
#define WPAD_ROWS 10112           // 79*128

// prep kernel block ranges (256 threads each)
#define PB_CVTX   1024            // 8192*512/16 = 262144 threads, 16 fp8/thread
#define PB_CVTW   1264            // 10112*512/16 = 323584 threads
#define PB_ROWS   1024            // 4096 rows, 4/block
#define PB_ZERO   8               // zero sumexp (8192 f32)
#define PB_TOTAL  (PB_CVTX + PB_CVTW + PB_ROWS + PB_ZERO)

typedef float f32x4 __attribute__((ext_vector_type(4)));
typedef int   i32x8 __attribute__((ext_vector_type(8)));

union F8frag { i32x8 v; uint4 q[2]; };

__device__ __forceinline__ void gll16(const void* g, void* l) {
  __builtin_amdgcn_global_load_lds(
      (const __attribute__((address_space(1))) void*)g,
      (__attribute__((address_space(3))) void*)l,
      16, 0, 0);
}

__device__ __forceinline__ unsigned pk_fp8x4(float4 a) {
  int v = __builtin_amdgcn_cvt_pk_fp8_f32(a.x, a.y, 0, false);
  v = __builtin_amdgcn_cvt_pk_fp8_f32(a.z, a.w, v, true);
  return (unsigned)v;
}

// ---- fused prep: cvt X->fp8, cvt W->fp8, per-row stats, zero sumexp ----
__global__ void prep_kernel(const float* __restrict__ sx, const float* __restrict__ hx,
                            const int* __restrict__ tgt,
                            const float* __restrict__ centers,
                            const float* __restrict__ weight,
                            uint4* __restrict__ X8, uint4* __restrict__ W8,
                            float* __restrict__ tlogit, float* __restrict__ qrow,
                            float4* __restrict__ sumexp4) {
  const int b   = blockIdx.x;
  const int tid = threadIdx.x;

  if (b < PB_CVTX) {
    // soft_x|hard_x -> fp8 X8 [8192][512]; 16 floats -> 16 bytes per thread
    int idx = b * 256 + tid;
    const int half = BATCH * FEATDIM / 16;         // 131072
    const float4* src = (idx < half) ? ((const float4*)sx) + (size_t)idx * 4
                                     : ((const float4*)hx) + (size_t)(idx - half) * 4;
    uint4 o;
    o.x = pk_fp8x4(src[0]);
    o.y = pk_fp8x4(src[1]);
    o.z = pk_fp8x4(src[2]);
    o.w = pk_fp8x4(src[3]);
    X8[idx] = o;
    return;
  }
  if (b < PB_CVTX + PB_CVTW) {
    // weight -> fp8 W8 [10112][512], pad rows zeroed
    int idx = (b - PB_CVTX) * 256 + tid;
    int row = idx >> 5;                            // 32 uint4 (512 B) per row
    uint4 o = {0u, 0u, 0u, 0u};
    if (row < NUM_CLASS) {
      const float4* src = ((const float4*)weight) + (size_t)idx * 4;
      o.x = pk_fp8x4(src[0]);
      o.y = pk_fp8x4(src[1]);
      o.z = pk_fp8x4(src[2]);
      o.w = pk_fp8x4(src[3]);
    }
    W8[idx] = o;
    return;
  }
  if (b < PB_CVTX + PB_CVTW + PB_ROWS) {
    // per-row: target logits (f32 exact) + quantization sum
    int row  = (b - PB_CVTX - PB_CVTW) * 4 + (tid >> 6);
    int lane = tid & 63;
    int t = tgt[row];
    const float4* s4 = (const float4*)(sx + (size_t)row * FEATDIM);
    const float4* h4 = (const float4*)(hx + (size_t)row * FEATDIM);
    const float4* c4 = (const float4*)(centers + (size_t)t * FEATDIM);
    const float4* w4 = (const float4*)(weight + (size_t)t * FEATDIM);
    float qs = 0.f, ds = 0.f, dh = 0.f;
#pragma unroll
    for (int j = 0; j < 2; ++j) {
      int i = lane + j * 64;
      float4 s = s4[i], h = h4[i], c = c4[i], w = w4[i];
      float d0 = s.x - c.x, d1 = s.y - c.y, d2 = s.z - c.z, d3 = s.w - c.w;
      float e0 = h.x - c.x, e1 = h.y - c.y, e2 = h.z - c.z, e3 = h.w - c.w;
      qs += d0*d0 + d1*d1 + d2*d2 + d3*d3 + e0*e0 + e1*e1 + e2*e2 + e3*e3;
      ds += s.x*w.x + s.y*w.y + s.z*w.z + s.w*w.w;
      dh += h.x*w.x + h.y*w.y + h.z*w.z + h.w*w.w;
    }
#pragma unroll
    for (int m = 1; m < 64; m <<= 1) {
      qs += __shfl_xor(qs, m);
      ds += __shfl_xor(ds, m);
      dh += __shfl_xor(dh, m);
    }
    if (lane == 0) {
      tlogit[row]         = ds;
      tlogit[BATCH + row] = dh;
      qrow[row]           = qs;
    }
    return;
  }
  // zero sumexp: 8 blocks x 256 threads x 1 float4 = 8192 f32
  {
    int idx = (b - PB_CVTX - PB_CVTW - PB_ROWS) * 256 + tid;
    float4 z = {0.f, 0.f, 0.f, 0.f};
    sumexp4[idx] = z;
  }
}

// ---- fused MX-fp8 GEMM + sum-of-exp over class axis ----
// grid: NSPLIT*ROWTILES, bid = chunk*64 + rowtile (chunk-major for W L2 locality)
// LDS layout (per tile row r, K-byte kb of this k-step):
//   col(kb, r) = (((kb>>4)&1)*64 + (kb>>5)*16 + (kb&15)) ^ ((r&7)<<4)
// chosen so fragment reads reproduce the bf16 kernel's measured-zero-conflict
// lane->address maps: lane(h,rl) reads (h*16)^sr and (64+h*16)^sr.
__launch_bounds__(256, 3)
__global__ void gemm_lse_kernel(const char* __restrict__ X8, const char* __restrict__ W8,
                                float* __restrict__ sumexp) {
  __shared__ char ldsA[BM * BKF];   // 16 KB
  __shared__ char ldsB[BN * BKF];   // 16 KB

  const int tid  = threadIdx.x;
  const int lane = tid & 63;
  const int w    = tid >> 6;
  const int wm   = w >> 1;          // 2x2 wave grid, each wave 64x64
  const int wn   = w & 1;
  const int chunk   = blockIdx.x >> 6;
  const int rowtile = blockIdx.x & 63;
  const int nt0 = (chunk * NTILES) / NSPLIT;
  const int nt1 = ((chunk + 1) * NTILES) / NSPLIT;

  // staging: 16 segs of 1KB per tile; wave w stages segs w*4..w*4+3 of each tile.
  // LDS dest linear (base + lane*16); source chunk chosen as the inverse of the
  // layout map above: cp = col ^ sr; kb = ((cp>>4)&3)*32 + ((cp>>6)&1)*16.
  int srow[4], skb[4];
#pragma unroll
  for (int j = 0; j < 4; ++j) {
    int seg = w * 4 + j;
    int o = seg * 1024 + lane * 16;
    int r = o >> 7;
    int cp = (o & 127) ^ ((r & 7) << 4);
    srow[j] = r;
    skb[j]  = ((cp >> 4) & 3) * 32 + ((cp >> 6) & 1) * 16;
  }

  float se[4][4];
#pragma unroll
  for (int mi = 0; mi < 4; ++mi)
#pragma unroll
    for (int r = 0; r < 4; ++r) se[mi][r] = 0.f;

  const int arow0 = rowtile * BM;
  const int rl  = lane & 15;
  const int h16 = (lane >> 4) << 4;      // h*16

  for (int nt = nt0; nt < nt1; ++nt) {
    f32x4 acc[4][4];
#pragma unroll
    for (int mi = 0; mi < 4; ++mi)
#pragma unroll
      for (int ni = 0; ni < 4; ++ni) {
        f32x4 z = {0.f, 0.f, 0.f, 0.f};
        acc[mi][ni] = z;
      }
    const int brow0 = nt * BN;

#pragma unroll 1
    for (int ks = 0; ks < KSTEPS; ++ks) {
      __syncthreads();                 // LDS reads of prev step done
#pragma unroll
      for (int j = 0; j < 4; ++j) {
        int seg = w * 4 + j;
        const char* ga = X8 + ((arow0 + srow[j]) * 512 + ks * 128 + skb[j]);
        gll16(ga, ldsA + seg * 1024);
        const char* gb = W8 + ((brow0 + srow[j]) * 512 + ks * 128 + skb[j]);
        gll16(gb, ldsB + seg * 1024);
      }
      __syncthreads();                 // drains vmcnt, staging complete

      F8frag a[4], b[4];
#pragma unroll
      for (int mi = 0; mi < 4; ++mi) {
        int r  = wm * 64 + mi * 16 + rl;
        int sr = (r & 7) << 4;
        const char* base = ldsA + r * 128;
        a[mi].q[0] = *(const uint4*)(base + (h16 ^ sr));        // kb [32h,32h+16)
        a[mi].q[1] = *(const uint4*)(base + ((64 + h16) ^ sr)); // kb [32h+16,32h+32)
      }
#pragma unroll
      for (int ni = 0; ni < 4; ++ni) {
        int r  = wn * 64 + ni * 16 + rl;
        int sr = (r & 7) << 4;
        const char* base = ldsB + r * 128;
        b[ni].q[0] = *(const uint4*)(base + (h16 ^ sr));
        b[ni].q[1] = *(const uint4*)(base + ((64 + h16) ^ sr));
      }
#pragma unroll
      for (int mi = 0; mi < 4; ++mi)
#pragma unroll
        for (int ni = 0; ni < 4; ++ni)
          acc[mi][ni] = __builtin_amdgcn_mfma_scale_f32_16x16x128_f8f6f4(
              a[mi].v, b[ni].v, acc[mi][ni],
              0, 0,                         // cbsz=FP8(A), blgp=FP8(B)
              0, 0x7F7F7F7F,                // opselA, scaleA = 1.0 (E8M0 127)
              0, 0x7F7F7F7F);               // opselB, scaleB = 1.0
    }

    // epilogue: sum exp over this 128-col tile; mask ragged cols >= NUM_CLASS
    const int colb = nt * BN + wn * 64 + rl;
#pragma unroll
    for (int ni = 0; ni < 4; ++ni) {
      bool ok = (colb + ni * 16) < NUM_CLASS;
#pragma unroll
      for (int mi = 0; mi < 4; ++mi)
#pragma unroll
        for (int r = 0; r < 4; ++r)
          if (ok) se[mi][r] += __expf(acc[mi][ni][r]);
    }
  }

  // C/D layout: col = lane&15 (summed over), row = (lane>>4)*4 + r
#pragma unroll
  for (int m = 1; m < 16; m <<= 1)
#pragma unroll
    for (int mi = 0; mi < 4; ++mi)
#pragma unroll
      for (int r = 0; r < 4; ++r)
        se[mi][r] += __shfl_xor(se[mi][r], m);

  if ((lane & 15) == 0) {
#pragma unroll
    for (int mi = 0; mi < 4; ++mi)
#pragma unroll
      for (int r = 0; r < 4; ++r) {
        int grow = arow0 + wm * 64 + mi * 16 + ((lane >> 4) << 2) + r;
        atomicAdd(&sumexp[grow], se[mi][r]);
      }
  }
}

// ---- final scalar reduction ----
__global__ void finalize_kernel(const float* __restrict__ sumexp,
                                const float* __restrict__ tlogit,
                                const float* __restrict__ qrow,
                                float* __restrict__ out) {
  int tid = threadIdx.x;     // 1024 threads
  float acc = 0.f, q = 0.f;
  for (int i = tid; i < MROWS; i += 1024)
    acc += logf(sumexp[i]) - tlogit[i];
  for (int i = tid; i < BATCH; i += 1024)
    q += qrow[i];
#pragma unroll
  for (int m = 1; m < 64; m <<= 1) {
    acc += __shfl_xor(acc, m);
    q   += __shfl_xor(q, m);
  }
  __shared__ float redA[16], redQ[16];
  if ((tid & 63) == 0) { redA[tid >> 6] = acc; redQ[tid >> 6] = q; }
  __syncthreads();
  if (tid == 0) {
    float s = 0.f, qq = 0.f;
#pragma unroll
    for (int i = 0; i < 16; ++i) { s += redA[i]; qq += redQ[i]; }
    // loss = (ce1_sum + ce2_sum)/B + PARAM * 0.5 * qsum / B ; PARAM=0.5, B=4096
    out[0] = s * (1.0f / BATCH) + qq * (1.0f / 16384.0f);
  }
}

extern "C" void kernel_launch(void* const* d_in, const int* in_sizes, int n_in,
                              void* d_out, int out_size, void* d_ws, size_t ws_size,
                              hipStream_t stream) {
  const float* sx = (const float*)d_in[0];
  const float* hx = (const float*)d_in[1];
  const int*   tg = (const int*)d_in[2];
  const float* ct = (const float*)d_in[3];
  const float* wt = (const float*)d_in[4];
  float* out = (float*)d_out;

  char* ws = (char*)d_ws;
  char* X8 = ws;                                               // 4,194,304 B
  char* W8 = ws + (size_t)MROWS * FEATDIM;                     // 5,177,344 B
  size_t off = (size_t)MROWS * FEATDIM + (size_t)WPAD_ROWS * FEATDIM;
  float* sumexp = (float*)(ws + off);                          // 8192 f32
  float* tlogit = (float*)(ws + off + (size_t)MROWS * 4);      // 8192 f32
  float* qrow   = (float*)(ws + off + (size_t)MROWS * 8);      // 4096 f32

  prep_kernel<<<PB_TOTAL, 256, 0, stream>>>(sx, hx, tg, ct, wt,
                                            (uint4*)X8, (uint4*)W8,
                                            tlogit, qrow, (float4*)sumexp);
  gemm_lse_kernel<<<NSPLIT * ROWTILES, 256, 0, stream>>>(X8, W8, sumexp);
  finalize_kernel<<<1, 1024, 0, stream>>>(sumexp, tlogit, qrow, out);
}